// Round 1
// baseline (227.118 us; speedup 1.0000x reference)
//
#include <hip/hip_runtime.h>
#include <hip/hip_bf16.h>
#include <stdint.h>

// Shapes (fixed by the problem)
#define B_ROWS 16384
#define VDIM   16
#define SDIM   64
#define HDIM   512
#define KDIM   1024   // V*S
#define KP     1056   // KDIM + 16 bias cols + 16 zero pad (multiple of 32)

using bf16x8 = __attribute__((ext_vector_type(8))) __bf16;
using f32x4  = __attribute__((ext_vector_type(4))) float;

__device__ __forceinline__ unsigned short f2bf(float f) {
  unsigned int u = __builtin_bit_cast(unsigned int, f);
  u = (u + 0x7FFFu + ((u >> 16) & 1u)) >> 16;   // RNE
  return (unsigned short)u;
}
__device__ __forceinline__ float bflo(unsigned int u) { return __builtin_bit_cast(float, u << 16); }
__device__ __forceinline__ float bfhi(unsigned int u) { return __builtin_bit_cast(float, u & 0xFFFF0000u); }

__device__ __forceinline__ void gl_lds16(const void* g, void* l) {
  __builtin_amdgcn_global_load_lds(
      (const __attribute__((address_space(1))) void*)(g),
      (__attribute__((address_space(3))) void*)(l),
      16, 0, 0);
}

// ---------------------------------------------------------------------------
// K0a: build Bt = [W_cat ; bias ; 0]^T as bf16, layout [HDIM][KP] (N-major,
// contiguous in k) so GEMM B-fragments are contiguous ds_read_b128.
__global__ __launch_bounds__(256) void k0a_build_bt(
    const float* __restrict__ W, const float* __restrict__ bias,
    unsigned short* __restrict__ Bt) {
  int idx = blockIdx.x * 256 + threadIdx.x;        // 1056*512 = 540672 exactly
  if (idx >= KP * HDIM) return;
  int k = idx >> 9;          // 0..1055
  int n = idx & 511;         // 0..511
  float val;
  if (k < KDIM)            val = W[(size_t)k * HDIM + n];          // coalesced
  else if (k < KDIM + 16)  val = bias[(size_t)(k - KDIM) * HDIM + n];
  else                     val = 0.f;
  Bt[(size_t)n * KP + k] = f2bf(val);
}

// ---------------------------------------------------------------------------
// K0b: W_comb[k][v'] = (sum_h W_cat[k][h] * W_sel[h][v'])/16  (bf16, [1024][16])
//      b_comb[v']   = mean_v(bias)[.] @ W_sel[:,v'] + b_sel[v']  (fp32, [16])
__global__ __launch_bounds__(256) void k0b_build_comb(
    const float* __restrict__ W, const float* __restrict__ bias,
    const float* __restrict__ Wsel, const float* __restrict__ bsel,
    unsigned short* __restrict__ Wcomb, float* __restrict__ bcomb) {
  if (blockIdx.x < 64) {
    int tg = blockIdx.x * 256 + threadIdx.x;   // 16384 threads = (k, v)
    int k = tg >> 4, v = tg & 15;
    const float* wr = W + (size_t)k * HDIM;
    float s = 0.f;
    for (int h = 0; h < HDIM; ++h) s = fmaf(wr[h], Wsel[h * VDIM + v], s);
    Wcomb[k * VDIM + v] = f2bf(s * (1.f / 16.f));
  } else {
    __shared__ float bm[HDIM];
    __shared__ float part[16][17];
    int t = threadIdx.x;
    for (int h = t; h < HDIM; h += 256) {
      float s = 0.f;
      #pragma unroll
      for (int v = 0; v < VDIM; ++v) s += bias[v * HDIM + h];
      bm[h] = s * (1.f / 16.f);
    }
    __syncthreads();
    int v = t & 15, sl = t >> 4;
    float s = 0.f;
    for (int h = sl * 32; h < sl * 32 + 32; ++h) s = fmaf(bm[h], Wsel[h * VDIM + v], s);
    part[sl][v] = s;
    __syncthreads();
    if (t < 16) {
      float s2 = bsel[t];
      #pragma unroll
      for (int i = 0; i < 16; ++i) s2 += part[i][t];
      bcomb[t] = s2;
    }
  }
}

// ---------------------------------------------------------------------------
// K1: per row b: logits = x_row @ W_comb + b_comb ; weights = softmax(logits);
//     A'[b][k<1024] = bf16(w[k>>6] * x[k]);  A'[b][1024+v] = bf16(w[v]); pad 0.
// One wave per row-task; 4 rows/wave; block = 4 waves → 16 rows/block.
__global__ __launch_bounds__(256) void k1_gate(
    const float* __restrict__ x, const unsigned short* __restrict__ Wcomb,
    const float* __restrict__ bcomb, unsigned short* __restrict__ Aout) {
  __shared__ uint4 wcq[2048];   // W_comb bf16 [1024][16] = 32 KiB
  const int t = threadIdx.x;
  const uint4* wg = (const uint4*)Wcomb;
  #pragma unroll
  for (int i = 0; i < 8; ++i) wcq[t + 256 * i] = wg[t + 256 * i];
  __syncthreads();

  const int wave = t >> 6, lane = t & 63;
  float bcv[16];
  #pragma unroll
  for (int v = 0; v < 16; ++v) bcv[v] = bcomb[v];

  for (int r = 0; r < 4; ++r) {
    const int b = blockIdx.x * 16 + wave * 4 + r;
    const float* xr = x + (size_t)b * KDIM;
    float pl[16];
    #pragma unroll
    for (int v = 0; v < 16; ++v) pl[v] = 0.f;
    float xv[16];
    #pragma unroll
    for (int i = 0; i < 16; ++i) {
      const int k = lane + 64 * i;          // note: v = k>>6 == i for this lane map
      const float xk = xr[k];
      xv[i] = xk;
      uint4 q0 = wcq[2 * k], q1 = wcq[2 * k + 1];
      pl[0]  = fmaf(xk, bflo(q0.x), pl[0]);  pl[1]  = fmaf(xk, bfhi(q0.x), pl[1]);
      pl[2]  = fmaf(xk, bflo(q0.y), pl[2]);  pl[3]  = fmaf(xk, bfhi(q0.y), pl[3]);
      pl[4]  = fmaf(xk, bflo(q0.z), pl[4]);  pl[5]  = fmaf(xk, bfhi(q0.z), pl[5]);
      pl[6]  = fmaf(xk, bflo(q0.w), pl[6]);  pl[7]  = fmaf(xk, bfhi(q0.w), pl[7]);
      pl[8]  = fmaf(xk, bflo(q1.x), pl[8]);  pl[9]  = fmaf(xk, bfhi(q1.x), pl[9]);
      pl[10] = fmaf(xk, bflo(q1.y), pl[10]); pl[11] = fmaf(xk, bfhi(q1.y), pl[11]);
      pl[12] = fmaf(xk, bflo(q1.z), pl[12]); pl[13] = fmaf(xk, bfhi(q1.z), pl[13]);
      pl[14] = fmaf(xk, bflo(q1.w), pl[14]); pl[15] = fmaf(xk, bfhi(q1.w), pl[15]);
    }
    // 64-lane butterfly reduce for all 16 logits
    #pragma unroll
    for (int off = 32; off > 0; off >>= 1) {
      #pragma unroll
      for (int v = 0; v < 16; ++v) pl[v] += __shfl_xor(pl[v], off, 64);
    }
    // softmax (every lane redundantly)
    float mx = -1e30f;
    #pragma unroll
    for (int v = 0; v < 16; ++v) { pl[v] += bcv[v]; mx = fmaxf(mx, pl[v]); }
    float s = 0.f, wv[16];
    #pragma unroll
    for (int v = 0; v < 16; ++v) { wv[v] = __expf(pl[v] - mx); s += wv[v]; }
    const float inv = 1.f / s;
    #pragma unroll
    for (int v = 0; v < 16; ++v) wv[v] *= inv;

    unsigned short* yr = Aout + (size_t)b * KP;
    #pragma unroll
    for (int i = 0; i < 16; ++i) yr[lane + 64 * i] = f2bf(wv[i] * xv[i]);
    // bias columns: w (bf16) then zeros
    float tail = 0.f;
    #pragma unroll
    for (int v = 0; v < 16; ++v) tail = (lane == v) ? wv[v] : tail;
    if (lane < 32) yr[KDIM + lane] = (lane < 16) ? f2bf(tail) : (unsigned short)0;
  }
}

// ---------------------------------------------------------------------------
// K2: C[16384][512] = A'[16384][1056] @ Bt[512][1056]^T   (bf16 MFMA, fp32 out)
// m97 structure: 128x128 tile, 4 waves (2x2 of 64x64), 16x16x32 MFMA,
// global_load_lds dwordx4 staging, 2-barrier K-loop, BK=32 (33 iters).
__global__ __launch_bounds__(256) void k2_gemm(
    const unsigned short* __restrict__ A, const unsigned short* __restrict__ Bt,
    float* __restrict__ C) {
  __shared__ unsigned short As[128 * 32];   // 8 KiB, [row][32k], row = 64 B
  __shared__ unsigned short Bs[128 * 32];   // 8 KiB, [n][32k]

  const int t = threadIdx.x;
  const int wave = t >> 6, lane = t & 63;
  const int tm = blockIdx.x >> 2, tn = blockIdx.x & 3;
  const int mlane = lane & 15, quad = lane >> 4;
  const int RM = (wave >> 1) * 64, CN = (wave & 1) * 64;

  // staging: 8 chunks of 1024 B each for As and Bs; wave w stages chunks 2w,2w+1
  const int srow = lane >> 2;           // 0..15 (row within chunk)
  const int scol = (lane & 3) * 8;      // k element offset (0,8,16,24)
  const int c0 = wave * 2;
  const unsigned short* ag0 = A  + (size_t)(tm * 128 + (c0 + 0) * 16 + srow) * KP + scol;
  const unsigned short* ag1 = A  + (size_t)(tm * 128 + (c0 + 1) * 16 + srow) * KP + scol;
  const unsigned short* bg0 = Bt + (size_t)(tn * 128 + (c0 + 0) * 16 + srow) * KP + scol;
  const unsigned short* bg1 = Bt + (size_t)(tn * 128 + (c0 + 1) * 16 + srow) * KP + scol;
  unsigned short* asd0 = &As[(c0 + 0) * 512];
  unsigned short* asd1 = &As[(c0 + 1) * 512];
  unsigned short* bsd0 = &Bs[(c0 + 0) * 512];
  unsigned short* bsd1 = &Bs[(c0 + 1) * 512];

  // fragment read pointers (constant across K iterations)
  const unsigned short* ap[4];
  const unsigned short* bp[4];
  #pragma unroll
  for (int i = 0; i < 4; ++i) {
    ap[i] = &As[(RM + i * 16 + mlane) * 32 + quad * 8];
    bp[i] = &Bs[(CN + i * 16 + mlane) * 32 + quad * 8];
  }

  f32x4 acc[4][4];
  const f32x4 z = {0.f, 0.f, 0.f, 0.f};
  #pragma unroll
  for (int i = 0; i < 4; ++i)
    #pragma unroll
    for (int j = 0; j < 4; ++j) acc[i][j] = z;

  for (int kt = 0; kt < KP / 32; ++kt) {
    gl_lds16(ag0, asd0); gl_lds16(ag1, asd1);
    gl_lds16(bg0, bsd0); gl_lds16(bg1, bsd1);
    ag0 += 32; ag1 += 32; bg0 += 32; bg1 += 32;
    __syncthreads();                       // vmcnt(0) drain + all waves staged
    bf16x8 af[4], bfv[4];
    #pragma unroll
    for (int i = 0; i < 4; ++i) af[i]  = *(const bf16x8*)ap[i];
    #pragma unroll
    for (int j = 0; j < 4; ++j) bfv[j] = *(const bf16x8*)bp[j];
    #pragma unroll
    for (int i = 0; i < 4; ++i)
      #pragma unroll
      for (int j = 0; j < 4; ++j)
        acc[i][j] = __builtin_amdgcn_mfma_f32_16x16x32_bf16(af[i], bfv[j], acc[i][j], 0, 0, 0);
    __syncthreads();                       // readers done before next stage
  }

  // epilogue: C/D layout col=lane&15, row=quad*4+reg  [m89/m91]
  const size_t rowb = (size_t)(tm * 128 + RM);
  const int colb = tn * 128 + CN;
  #pragma unroll
  for (int i = 0; i < 4; ++i)
    #pragma unroll
    for (int j = 0; j < 4; ++j)
      #pragma unroll
      for (int r = 0; r < 4; ++r) {
        const size_t row = rowb + i * 16 + quad * 4 + r;
        const int col = colb + j * 16 + mlane;
        C[row * HDIM + col] = acc[i][j][r];
      }
}

// ---------------------------------------------------------------------------
extern "C" void kernel_launch(void* const* d_in, const int* in_sizes, int n_in,
                              void* d_out, int out_size, void* d_ws, size_t ws_size,
                              hipStream_t stream) {
  const float* x    = (const float*)d_in[0];   // [B, V, S] = [16384][1024] flat
  const float* W    = (const float*)d_in[1];   // [V, S, H] = [1024][512] flat
  const float* bias = (const float*)d_in[2];   // [V, H]
  const float* Wsel = (const float*)d_in[3];   // [H, V]
  const float* bsel = (const float*)d_in[4];   // [V]
  float* out = (float*)d_out;                  // [B, H] fp32

  char* ws = (char*)d_ws;
  unsigned short* Bt    = (unsigned short*)(ws);            // 512*1056*2 = 1,081,344 B
  unsigned short* Wcomb = (unsigned short*)(ws + 1081344);  // 1024*16*2  =    32,768 B
  float*          bcomb = (float*)(ws + 1114112);           // 16*4       (padded to 256)
  unsigned short* Ax    = (unsigned short*)(ws + 1114368);  // 16384*1056*2 = 34,603,008 B

  k0a_build_bt<<<2112, 256, 0, stream>>>(W, bias, Bt);
  k0b_build_comb<<<65, 256, 0, stream>>>(W, bias, Wsel, bsel, Wcomb, bcomb);
  k1_gate<<<1024, 256, 0, stream>>>(x, Wcomb, bcomb, Ax);
  k2_gemm<<<512, 256, 0, stream>>>(Ax, Bt, out);
}

// Round 2
// 171.542 us; speedup vs baseline: 1.3240x; 1.3240x over previous
//
#include <hip/hip_runtime.h>
#include <hip/hip_bf16.h>
#include <stdint.h>

// Shapes (fixed by the problem)
#define B_ROWS 16384
#define VDIM   16
#define SDIM   64
#define HDIM   512
#define KDIM   1024   // V*S
#define KP     1056   // KDIM + 16 bias cols + 16 zero pad (multiple of 32)

using bf16x8 = __attribute__((ext_vector_type(8))) __bf16;
using u16x8  = __attribute__((ext_vector_type(8))) unsigned short;
using f32x4  = __attribute__((ext_vector_type(4))) float;

__device__ __forceinline__ unsigned short f2bf(float f) {
  unsigned int u = __builtin_bit_cast(unsigned int, f);
  u = (u + 0x7FFFu + ((u >> 16) & 1u)) >> 16;   // RNE
  return (unsigned short)u;
}

__device__ __forceinline__ void gl_lds16(const void* g, void* l) {
  __builtin_amdgcn_global_load_lds(
      (const __attribute__((address_space(1))) void*)(g),
      (__attribute__((address_space(3))) void*)(l),
      16, 0, 0);
}

// ---------------------------------------------------------------------------
// K0a: build Bt = [W_cat ; bias ; 0]^T as bf16, layout [HDIM][KP] (N-major,
// contiguous in k) so GEMM B-fragments are contiguous ds_read_b128.
__global__ __launch_bounds__(256) void k0a_build_bt(
    const float* __restrict__ W, const float* __restrict__ bias,
    unsigned short* __restrict__ Bt) {
  int idx = blockIdx.x * 256 + threadIdx.x;        // 1056*512 = 540672 exactly
  if (idx >= KP * HDIM) return;
  int k = idx >> 9;          // 0..1055
  int n = idx & 511;         // 0..511
  float val;
  if (k < KDIM)            val = W[(size_t)k * HDIM + n];          // coalesced
  else if (k < KDIM + 16)  val = bias[(size_t)(k - KDIM) * HDIM + n];
  else                     val = 0.f;
  Bt[(size_t)n * KP + k] = f2bf(val);
}

// ---------------------------------------------------------------------------
// K0b: WcombT[v][k] = bf16( dot(W[k,:], Wsel[:,v]) / 16 )   [16][1024]
//      bcomb[v]     = mean_v(bias) @ Wsel[:,v] + bsel[v]    (fp32, block 256)
// blocks 0..255: 4 waves, one k-row per wave. 1024 waves total, no serial
// 512-deep chains (lane h-split 8-way + 96-shuffle reduce, tiny scale).
__global__ __launch_bounds__(256) void k0b_comb(
    const float* __restrict__ W, const float* __restrict__ bias,
    const float* __restrict__ Wsel, const float* __restrict__ bsel,
    unsigned short* __restrict__ WcombT, float* __restrict__ bcomb) {
  __shared__ float wsl[512 * 17];      // padded stride 17: conflict-free
  __shared__ float bm[HDIM];
  __shared__ float part[16][17];
  const int t = threadIdx.x;
  if (blockIdx.x < 256) {
    for (int i = t; i < 512 * 16; i += 256) {
      int h = i >> 4, v = i & 15;
      wsl[h * 17 + v] = Wsel[i];
    }
    __syncthreads();
    const int wave = t >> 6, lane = t & 63;
    const int k = blockIdx.x * 4 + wave;
    const float* wr = W + (size_t)k * HDIM;
    float s[16];
    #pragma unroll
    for (int v = 0; v < 16; ++v) s[v] = 0.f;
    #pragma unroll
    for (int j = 0; j < 8; ++j) {
      const int h = lane + 64 * j;     // coalesced W reads, spread LDS banks
      const float a = wr[h];
      const float* wl = &wsl[h * 17];
      #pragma unroll
      for (int v = 0; v < 16; ++v) s[v] = fmaf(a, wl[v], s[v]);
    }
    #pragma unroll
    for (int off = 32; off > 0; off >>= 1) {
      #pragma unroll
      for (int v = 0; v < 16; ++v) s[v] += __shfl_xor(s[v], off, 64);
    }
    float mine = 0.f;
    #pragma unroll
    for (int v = 0; v < 16; ++v) mine = (lane == v) ? s[v] : mine;
    if (lane < 16) WcombT[lane * KDIM + k] = f2bf(mine * (1.f / 16.f));
  } else {
    // bcomb (one block)
    for (int h = t; h < HDIM; h += 256) {
      float s = 0.f;
      #pragma unroll
      for (int v = 0; v < VDIM; ++v) s += bias[v * HDIM + h];
      bm[h] = s * (1.f / 16.f);
    }
    __syncthreads();
    int v = t & 15, sl = t >> 4;
    float s = 0.f;
    for (int h = sl * 32; h < sl * 32 + 32; ++h) s = fmaf(bm[h], Wsel[h * VDIM + v], s);
    part[sl][v] = s;
    __syncthreads();
    if (t < 16) {
      float s2 = bsel[t];
      #pragma unroll
      for (int i = 0; i < 16; ++i) s2 += part[i][t];
      bcomb[t] = s2;
    }
  }
}

// ---------------------------------------------------------------------------
// K1a: partial logits via MFMA, no LDS, no shuffles.
// wave = (row-tile rt of 16 rows, K-segment seg of 256). 4096 waves.
// A-frag: x rows cast fp32->bf16 in-reg.  B-frag: WcombT rows (contig b128).
// part[row][seg*16+v] fp32.
__global__ __launch_bounds__(256) void k1a_logits(
    const float* __restrict__ x, const unsigned short* __restrict__ WcombT,
    float* __restrict__ part) {
  const int gw = blockIdx.x * 4 + (threadIdx.x >> 6);
  const int lane = threadIdx.x & 63;
  const int rt = gw >> 2, seg = gw & 3;
  const int m = lane & 15, quad = lane >> 4;
  const float* xr = x + (size_t)(rt * 16 + m) * KDIM + seg * 256 + quad * 8;
  const unsigned short* br = WcombT + m * KDIM + seg * 256 + quad * 8;
  f32x4 acc = {0.f, 0.f, 0.f, 0.f};
  #pragma unroll
  for (int kt = 0; kt < 8; ++kt) {
    float4 a0 = *(const float4*)(xr);
    float4 a1 = *(const float4*)(xr + 4);
    xr += 32;
    u16x8 u;
    u[0] = f2bf(a0.x); u[1] = f2bf(a0.y); u[2] = f2bf(a0.z); u[3] = f2bf(a0.w);
    u[4] = f2bf(a1.x); u[5] = f2bf(a1.y); u[6] = f2bf(a1.z); u[7] = f2bf(a1.w);
    bf16x8 af = __builtin_bit_cast(bf16x8, u);
    bf16x8 bfv = *(const bf16x8*)(br);
    br += 32;
    acc = __builtin_amdgcn_mfma_f32_16x16x32_bf16(af, bfv, acc, 0, 0, 0);
  }
  // C layout: col(v) = lane&15, row = quad*4 + r
  float* pr = part + (size_t)(rt * 16 + quad * 4) * 64 + seg * 16 + m;
  #pragma unroll
  for (int r = 0; r < 4; ++r) pr[(size_t)r * 64] = acc[r];
}

// ---------------------------------------------------------------------------
// K1b0: thread-per-row softmax; writes weights[row][16] fp32 and the 32
// bf16 tail columns of A' (w values then zeros).
__global__ __launch_bounds__(256) void k1b0_softmax(
    const float* __restrict__ part, const float* __restrict__ bcomb,
    float* __restrict__ weights, unsigned short* __restrict__ Ax) {
  const int row = blockIdx.x * 256 + threadIdx.x;
  const float* p = part + (size_t)row * 64;
  float l[16];
  float mx = -1e30f;
  #pragma unroll
  for (int v = 0; v < 16; ++v) {
    l[v] = bcomb[v] + p[v] + p[16 + v] + p[32 + v] + p[48 + v];
    mx = fmaxf(mx, l[v]);
  }
  float s = 0.f;
  #pragma unroll
  for (int v = 0; v < 16; ++v) { l[v] = __expf(l[v] - mx); s += l[v]; }
  const float inv = 1.f / s;
  float4* wout = (float4*)(weights + (size_t)row * 16);
  #pragma unroll
  for (int q = 0; q < 4; ++q) {
    float4 f;
    f.x = l[4 * q + 0] * inv; f.y = l[4 * q + 1] * inv;
    f.z = l[4 * q + 2] * inv; f.w = l[4 * q + 3] * inv;
    wout[q] = f;
  }
  // tail: A'[row][1024+v] = bf16(w[v]); [1040..1056) = 0
  unsigned short tb[16];
  #pragma unroll
  for (int v = 0; v < 16; ++v) tb[v] = f2bf(l[v] * inv);
  uint4* tp = (uint4*)(Ax + (size_t)row * KP + KDIM);
  tp[0] = *(const uint4*)(&tb[0]);
  tp[1] = *(const uint4*)(&tb[8]);
  uint4 z; z.x = 0; z.y = 0; z.z = 0; z.w = 0;
  tp[2] = z;
  tp[3] = z;
}

// ---------------------------------------------------------------------------
// K1b: scale-and-pack. wave-per-row, lane owns k=[16*lane,16*lane+16) so
// v = lane>>2 is lane-constant: zero cross-lane ops. Fully coalesced.
__global__ __launch_bounds__(256) void k1b_scale(
    const float* __restrict__ x, const float* __restrict__ weights,
    unsigned short* __restrict__ Ax) {
  const int wave = threadIdx.x >> 6, lane = threadIdx.x & 63;
  #pragma unroll
  for (int r = 0; r < 2; ++r) {
    const int row = blockIdx.x * 8 + wave * 2 + r;
    const float w = weights[(size_t)row * 16 + (lane >> 2)];
    const float4* xr = (const float4*)(x + (size_t)row * KDIM + lane * 16);
    float4 v0 = xr[0], v1 = xr[1], v2 = xr[2], v3 = xr[3];
    unsigned short o[16];
    o[0]  = f2bf(w * v0.x); o[1]  = f2bf(w * v0.y); o[2]  = f2bf(w * v0.z); o[3]  = f2bf(w * v0.w);
    o[4]  = f2bf(w * v1.x); o[5]  = f2bf(w * v1.y); o[6]  = f2bf(w * v1.z); o[7]  = f2bf(w * v1.w);
    o[8]  = f2bf(w * v2.x); o[9]  = f2bf(w * v2.y); o[10] = f2bf(w * v2.z); o[11] = f2bf(w * v2.w);
    o[12] = f2bf(w * v3.x); o[13] = f2bf(w * v3.y); o[14] = f2bf(w * v3.z); o[15] = f2bf(w * v3.w);
    uint4* yp = (uint4*)(Ax + (size_t)row * KP + lane * 16);
    yp[0] = *(const uint4*)(&o[0]);
    yp[1] = *(const uint4*)(&o[8]);
  }
}

// ---------------------------------------------------------------------------
// K2: C[16384][512] = A'[16384][1056] @ Bt[512][1056]^T   (bf16 MFMA, fp32 out)
// m97 structure: 128x128 tile, 4 waves (2x2 of 64x64), 16x16x32 MFMA,
// global_load_lds dwordx4 staging, 2-barrier K-loop, BK=32 (33 iters).
__global__ __launch_bounds__(256) void k2_gemm(
    const unsigned short* __restrict__ A, const unsigned short* __restrict__ Bt,
    float* __restrict__ C) {
  __shared__ unsigned short As[128 * 32];   // 8 KiB, [row][32k], row = 64 B
  __shared__ unsigned short Bs[128 * 32];   // 8 KiB, [n][32k]

  const int t = threadIdx.x;
  const int wave = t >> 6, lane = t & 63;
  const int tm = blockIdx.x >> 2, tn = blockIdx.x & 3;
  const int mlane = lane & 15, quad = lane >> 4;
  const int RM = (wave >> 1) * 64, CN = (wave & 1) * 64;

  // staging: 8 chunks of 1024 B each for As and Bs; wave w stages chunks 2w,2w+1
  const int srow = lane >> 2;           // 0..15 (row within chunk)
  const int scol = (lane & 3) * 8;      // k element offset (0,8,16,24)
  const int c0 = wave * 2;
  const unsigned short* ag0 = A  + (size_t)(tm * 128 + (c0 + 0) * 16 + srow) * KP + scol;
  const unsigned short* ag1 = A  + (size_t)(tm * 128 + (c0 + 1) * 16 + srow) * KP + scol;
  const unsigned short* bg0 = Bt + (size_t)(tn * 128 + (c0 + 0) * 16 + srow) * KP + scol;
  const unsigned short* bg1 = Bt + (size_t)(tn * 128 + (c0 + 1) * 16 + srow) * KP + scol;
  unsigned short* asd0 = &As[(c0 + 0) * 512];
  unsigned short* asd1 = &As[(c0 + 1) * 512];
  unsigned short* bsd0 = &Bs[(c0 + 0) * 512];
  unsigned short* bsd1 = &Bs[(c0 + 1) * 512];

  // fragment read pointers (constant across K iterations)
  const unsigned short* ap[4];
  const unsigned short* bp[4];
  #pragma unroll
  for (int i = 0; i < 4; ++i) {
    ap[i] = &As[(RM + i * 16 + mlane) * 32 + quad * 8];
    bp[i] = &Bs[(CN + i * 16 + mlane) * 32 + quad * 8];
  }

  f32x4 acc[4][4];
  const f32x4 z = {0.f, 0.f, 0.f, 0.f};
  #pragma unroll
  for (int i = 0; i < 4; ++i)
    #pragma unroll
    for (int j = 0; j < 4; ++j) acc[i][j] = z;

  for (int kt = 0; kt < KP / 32; ++kt) {
    gl_lds16(ag0, asd0); gl_lds16(ag1, asd1);
    gl_lds16(bg0, bsd0); gl_lds16(bg1, bsd1);
    ag0 += 32; ag1 += 32; bg0 += 32; bg1 += 32;
    __syncthreads();                       // vmcnt(0) drain + all waves staged
    bf16x8 af[4], bfv[4];
    #pragma unroll
    for (int i = 0; i < 4; ++i) af[i]  = *(const bf16x8*)ap[i];
    #pragma unroll
    for (int j = 0; j < 4; ++j) bfv[j] = *(const bf16x8*)bp[j];
    #pragma unroll
    for (int i = 0; i < 4; ++i)
      #pragma unroll
      for (int j = 0; j < 4; ++j)
        acc[i][j] = __builtin_amdgcn_mfma_f32_16x16x32_bf16(af[i], bfv[j], acc[i][j], 0, 0, 0);
    __syncthreads();                       // readers done before next stage
  }

  // epilogue: C/D layout col=lane&15, row=quad*4+reg  [m89/m91]
  const size_t rowb = (size_t)(tm * 128 + RM);
  const int colb = tn * 128 + CN;
  #pragma unroll
  for (int i = 0; i < 4; ++i)
    #pragma unroll
    for (int j = 0; j < 4; ++j)
      #pragma unroll
      for (int r = 0; r < 4; ++r) {
        const size_t row = rowb + i * 16 + quad * 4 + r;
        const int col = colb + j * 16 + mlane;
        C[row * HDIM + col] = acc[i][j][r];
      }
}

// ---------------------------------------------------------------------------
extern "C" void kernel_launch(void* const* d_in, const int* in_sizes, int n_in,
                              void* d_out, int out_size, void* d_ws, size_t ws_size,
                              hipStream_t stream) {
  const float* x    = (const float*)d_in[0];   // [B, V, S] = [16384][1024] flat
  const float* W    = (const float*)d_in[1];   // [V, S, H] = [1024][512] flat
  const float* bias = (const float*)d_in[2];   // [V, H]
  const float* Wsel = (const float*)d_in[3];   // [H, V]
  const float* bsel = (const float*)d_in[4];   // [V]
  float* out = (float*)d_out;                  // [B, H] fp32

  char* ws = (char*)d_ws;
  unsigned short* Bt     = (unsigned short*)(ws);            // 512*1056*2 = 1,081,344 B
  unsigned short* WcombT = (unsigned short*)(ws + 1081344);  // 16*1024*2  =    32,768 B
  float*          bcomb  = (float*)(ws + 1114112);           // 16*4 (padded to 256)
  float*          part   = (float*)(ws + 1114368);           // 16384*64*4 = 4,194,304 B
  float*          wts    = (float*)(ws + 5308672);           // 16384*16*4 = 1,048,576 B
  unsigned short* Ax     = (unsigned short*)(ws + 6357248);  // 16384*1056*2 = 34,603,008 B

  k0a_build_bt<<<2112, 256, 0, stream>>>(W, bias, Bt);
  k0b_comb<<<257, 256, 0, stream>>>(W, bias, Wsel, bsel, WcombT, bcomb);
  k1a_logits<<<1024, 256, 0, stream>>>(x, WcombT, part);
  k1b0_softmax<<<64, 256, 0, stream>>>(part, bcomb, wts, Ax);
  k1b_scale<<<2048, 256, 0, stream>>>(x, wts, Ax);
  k2_gemm<<<512, 256, 0, stream>>>(Ax, Bt, out);
}